// Round 12
// baseline (1442.893 us; speedup 1.0000x reference)
//
#include <hip/hip_runtime.h>
#include <hip/hip_bf16.h>
#include <cstdint>

// ---------------------------------------------------------------------------
// SAGE GNN, 2 layers, N=50000, E=800000, D: 128 -> 256 -> 128.
// 6 kernels:
//   setup:    bhist rows (blocks 0..PB-1) + bf16^T weights + A1[:,128:256]
//   colscan:  one wave per bucket: shfl-scan PB per-block counts -> prefixes+btot
//   bin2:     btot scan + own-prefix row -> cursors; bin edges -> stage; brow
//   agg1s:    block/bucket: LDS fp32 accumulator (64x128), consume stage
//             directly (no col/rowptr!), A1[:,0:128] = mean_in(bf16 x)
//   gemm_fused: h = relu(A1@W1+b1) -> LDS (swizzled); hw2 = h@[W2l|W2r]
//   agg2s:    same structure; out = mean_in(hw2[:,:128]) + hw2[:,128:] + b2
// ---------------------------------------------------------------------------

static inline size_t align_up(size_t x, size_t a) { return (x + a - 1) & ~(a - 1); }

using short8 = __attribute__((ext_vector_type(8))) short;
using f32x4  = __attribute__((ext_vector_type(4))) float;

#define BSHIFT 6   // 64 nodes per bucket; NB = ceil(N/64) = 782 (<= 1024)
#define PB 128     // partition blocks for hist/bin (<= 128 for colscan)

__device__ __forceinline__ float bfpair_lo(unsigned int v) {
  union { unsigned int i; float f; } u; u.i = v << 16; return u.f;
}
__device__ __forceinline__ float bfpair_hi(unsigned int v) {
  union { unsigned int i; float f; } u; u.i = v & 0xffff0000u; return u.f;
}
__device__ __forceinline__ unsigned short f2bf(float f) {
  union { float f; unsigned int i; } u; u.f = f;
  unsigned int r = u.i + 0x7fffu + ((u.i >> 16) & 1u);
  return (unsigned short)(r >> 16);
}

__device__ __forceinline__ void gload_lds16(const void* g, void* l) {
  __builtin_amdgcn_global_load_lds(
      (const __attribute__((address_space(1))) void*)g,
      (__attribute__((address_space(3))) void*)l, 16, 0, 0);
}

// ------------------- setup: bhist + weights + x convert --------------------
__global__ __launch_bounds__(256) void setup_kernel(
    const int* __restrict__ dst, int* __restrict__ blockhist, int E, int chunk,
    const float* __restrict__ x,
    const float* __restrict__ W1l, const float* __restrict__ W1r,
    const float* __restrict__ W2l, const float* __restrict__ W2r,
    __hip_bfloat16* __restrict__ BT1, __hip_bfloat16* __restrict__ BT2,
    __hip_bfloat16* __restrict__ A1, int total4) {
  __shared__ int h[1024];
  const int bb = blockIdx.x;
  const int t = threadIdx.x;
  if (bb < PB) {  // per-block bucket histogram, plain coalesced row stores
    #pragma unroll
    for (int i = t; i < 1024; i += 256) h[i] = 0;
    __syncthreads();
    const int e0 = bb * chunk;
    int e1 = e0 + chunk; if (e1 > E) e1 = E;
    for (int e = e0 + t; e < e1; e += 256) atomicAdd(&h[dst[e] >> BSHIFT], 1);
    __syncthreads();
    #pragma unroll
    for (int i = t; i < 1024; i += 256) blockhist[bb * 1024 + i] = h[i];
    return;
  }
  const int wb = bb - PB;
  if (wb < 512) {  // weights: BT1[n][k], BT2[n][k]
    int idx = (wb & 255) * 256 + t;
    int n = idx >> 8, k = idx & 255;
    if (wb < 256) {
      float v = (k < 128) ? W1l[k * 256 + n] : W1r[(k - 128) * 256 + n];
      BT1[idx] = __float2bfloat16(v);
    } else {
      float v = (n < 128) ? W2l[k * 128 + n] : W2r[k * 128 + (n - 128)];
      BT2[idx] = __float2bfloat16(v);
    }
    return;
  }
  int idx = (wb - 512) * 256 + t;
  if (idx >= total4) return;
  int i = idx >> 5, j4 = (idx & 31) << 2;
  float4 v = *reinterpret_cast<const float4*>(x + (size_t)i * 128 + j4);
  unsigned p0 = ((unsigned)f2bf(v.y) << 16) | f2bf(v.x);
  unsigned p1 = ((unsigned)f2bf(v.w) << 16) | f2bf(v.z);
  *reinterpret_cast<uint2*>(A1 + (size_t)i * 256 + 128 + j4) = make_uint2(p0, p1);
}

// ---------- colscan: one wave per bucket, shfl-scan over PB blocks ---------
__global__ __launch_bounds__(256) void colscan_kernel(int* __restrict__ blockhist,
                                                      int* __restrict__ btot) {
  const int t = threadIdx.x;
  const int lane = t & 63;
  const int i = blockIdx.x * 4 + (t >> 6);  // bucket id, grid = 256 blocks
  int v0 = blockhist[lane * 1024 + i];
  int v1 = (64 + lane < PB) ? blockhist[(64 + lane) * 1024 + i] : 0;
  int s0 = v0, s1 = v1;
  #pragma unroll
  for (int off = 1; off < 64; off <<= 1) {
    int u0 = __shfl_up(s0, off, 64);
    int u1 = __shfl_up(s1, off, 64);
    if (lane >= off) { s0 += u0; s1 += u1; }
  }
  const int total0 = __shfl(s0, 63, 64);
  const int total1 = __shfl(s1, 63, 64);
  blockhist[lane * 1024 + i] = s0 - v0;
  if (64 + lane < PB) blockhist[(64 + lane) * 1024 + i] = total0 + s1 - v1;
  if (lane == 0) btot[i] = total0 + total1;
}

// --------------- bin2: bucket-base scan + bin (all coalesced) --------------
__global__ __launch_bounds__(256) void bin2_kernel(const int* __restrict__ src,
                                                   const int* __restrict__ dst,
                                                   const int* __restrict__ blockhist,
                                                   const int* __restrict__ btot,
                                                   unsigned* __restrict__ stage,
                                                   int* __restrict__ brow,
                                                   int E, int NB, int chunk) {
  __shared__ int cur_lds[1024];
  __shared__ int wsum[4];
  const int t = threadIdx.x;
  const int pb = blockIdx.x;

  // block-wide exclusive scan of the 1024 bucket totals
  int4 v = *reinterpret_cast<const int4*>(btot + t * 4);
  int tsum = v.x + v.y + v.z + v.w;
  const int lane = t & 63, w = t >> 6;
  int inc = tsum;
  #pragma unroll
  for (int off = 1; off < 64; off <<= 1) {
    int u = __shfl_up(inc, off, 64);
    if (lane >= off) inc += u;
  }
  if (lane == 63) wsum[w] = inc;
  __syncthreads();
  int woff = 0;
  for (int k = 0; k < w; ++k) woff += wsum[k];
  int e0x = woff + inc - tsum;
  int p0 = e0x, p1 = p0 + v.x, p2 = p1 + v.y, p3 = p2 + v.z;

  // cursors = bucket base + this block's own prefix (coalesced int4 row read)
  int4 o = *reinterpret_cast<const int4*>(blockhist + pb * 1024 + t * 4);
  cur_lds[t * 4 + 0] = p0 + o.x;
  cur_lds[t * 4 + 1] = p1 + o.y;
  cur_lds[t * 4 + 2] = p2 + o.z;
  cur_lds[t * 4 + 3] = p3 + o.w;
  if (pb == 0) {  // publish brow for the agg kernels
    if (t * 4 + 0 < NB) brow[t * 4 + 0] = p0;
    if (t * 4 + 1 < NB) brow[t * 4 + 1] = p1;
    if (t * 4 + 2 < NB) brow[t * 4 + 2] = p2;
    if (t * 4 + 3 < NB) brow[t * 4 + 3] = p3;
    if (t == 255) brow[NB] = p3 + v.w;
  }
  __syncthreads();

  // bin this block's edge chunk via LDS cursors
  const int e0 = pb * chunk;
  const int e1 = min(e0 + chunk, E);
  for (int e = e0 + t; e < e1; e += 256) {
    int d = dst[e];
    int p = atomicAdd(&cur_lds[d >> BSHIFT], 1);
    stage[p] = (unsigned)src[e] | ((unsigned)(d & 63) << 16);
  }
}

// ---------------- stage-driven aggregations (no col/rowptr) ----------------
// block per bucket; LDS fp32 accumulator acc[64][128] (32 KB) + dcnt[64].
// Full wave per entry: 64 lanes x 4B = one 256B row load; unroll 8 -> 8 rows
// in flight per wave. ds_add_f32 accumulate into acc[dstLocal].

// A1[n][0:128] = mean over in-neighbors of A1[s][128:256]
__global__ __launch_bounds__(256) void agg1s_kernel(const unsigned* __restrict__ stage,
                                                    const int* __restrict__ brow,
                                                    __hip_bfloat16* __restrict__ A1,
                                                    int N) {
  __shared__ float acc[64 * 128];
  __shared__ int dcnt[64];
  const int b = blockIdx.x;
  const int t = threadIdx.x;
  const int lane = t & 63;
  const int wv = t >> 6;
  const int n0 = b << BSHIFT;
  const int lo = brow[b], hi = brow[b + 1];

  float4* az = reinterpret_cast<float4*>(acc);
  #pragma unroll
  for (int i = t; i < 2048; i += 256) az[i] = make_float4(0.f, 0.f, 0.f, 0.f);
  if (t < 64) dcnt[t] = 0;
  __syncthreads();

  int e = lo + wv;
  for (; e + 28 < hi; e += 32) {
    unsigned m[8], v[8];
    #pragma unroll
    for (int k = 0; k < 8; ++k) m[k] = stage[e + 4 * k];
    #pragma unroll
    for (int k = 0; k < 8; ++k)
      v[k] = *reinterpret_cast<const unsigned*>(
          (const char*)A1 + (size_t)(m[k] & 0xffffu) * 512 + 256 + lane * 4);
    #pragma unroll
    for (int k = 0; k < 8; ++k) {
      const int dl = m[k] >> 16;
      atomicAdd(&acc[dl * 128 + lane * 2 + 0], bfpair_lo(v[k]));
      atomicAdd(&acc[dl * 128 + lane * 2 + 1], bfpair_hi(v[k]));
      if (lane == 0) atomicAdd(&dcnt[dl], 1);
    }
  }
  for (; e < hi; e += 4) {
    unsigned m = stage[e];
    unsigned v = *reinterpret_cast<const unsigned*>(
        (const char*)A1 + (size_t)(m & 0xffffu) * 512 + 256 + lane * 4);
    const int dl = m >> 16;
    atomicAdd(&acc[dl * 128 + lane * 2 + 0], bfpair_lo(v));
    atomicAdd(&acc[dl * 128 + lane * 2 + 1], bfpair_hi(v));
    if (lane == 0) atomicAdd(&dcnt[dl], 1);
  }
  __syncthreads();

  // epilogue: 4 threads per node, each writes 32 floats -> 16 bf16-pairs
  const int node = t >> 2;
  const int gq = (t & 3) * 32;
  const int n = n0 + node;
  if (n < N) {
    const int d = dcnt[node];
    const float inv = 1.0f / (float)(d > 1 ? d : 1);
    #pragma unroll
    for (int j = 0; j < 32; j += 4) {
      float f0 = acc[node * 128 + gq + j + 0] * inv;
      float f1 = acc[node * 128 + gq + j + 1] * inv;
      float f2 = acc[node * 128 + gq + j + 2] * inv;
      float f3 = acc[node * 128 + gq + j + 3] * inv;
      unsigned pA = ((unsigned)f2bf(f1) << 16) | f2bf(f0);
      unsigned pB = ((unsigned)f2bf(f3) << 16) | f2bf(f2);
      *reinterpret_cast<uint2*>(A1 + (size_t)n * 256 + gq + j) = make_uint2(pA, pB);
    }
  }
}

// out[n] = mean_in(hw2[:,:128]) + hw2[n,128:] + b2   (fp32 out)
__global__ __launch_bounds__(256) void agg2s_kernel(const unsigned* __restrict__ stage,
                                                    const int* __restrict__ brow,
                                                    const __hip_bfloat16* __restrict__ hw2,
                                                    const float* __restrict__ b2,
                                                    float* __restrict__ out,
                                                    int N) {
  __shared__ float acc[64 * 128];
  __shared__ int dcnt[64];
  const int b = blockIdx.x;
  const int t = threadIdx.x;
  const int lane = t & 63;
  const int wv = t >> 6;
  const int n0 = b << BSHIFT;
  const int lo = brow[b], hi = brow[b + 1];

  float4* az = reinterpret_cast<float4*>(acc);
  #pragma unroll
  for (int i = t; i < 2048; i += 256) az[i] = make_float4(0.f, 0.f, 0.f, 0.f);
  if (t < 64) dcnt[t] = 0;
  __syncthreads();

  int e = lo + wv;
  for (; e + 28 < hi; e += 32) {
    unsigned m[8], v[8];
    #pragma unroll
    for (int k = 0; k < 8; ++k) m[k] = stage[e + 4 * k];
    #pragma unroll
    for (int k = 0; k < 8; ++k)
      v[k] = *reinterpret_cast<const unsigned*>(
          (const char*)hw2 + (size_t)(m[k] & 0xffffu) * 512 + lane * 4);
    #pragma unroll
    for (int k = 0; k < 8; ++k) {
      const int dl = m[k] >> 16;
      atomicAdd(&acc[dl * 128 + lane * 2 + 0], bfpair_lo(v[k]));
      atomicAdd(&acc[dl * 128 + lane * 2 + 1], bfpair_hi(v[k]));
      if (lane == 0) atomicAdd(&dcnt[dl], 1);
    }
  }
  for (; e < hi; e += 4) {
    unsigned m = stage[e];
    unsigned v = *reinterpret_cast<const unsigned*>(
        (const char*)hw2 + (size_t)(m & 0xffffu) * 512 + lane * 4);
    const int dl = m >> 16;
    atomicAdd(&acc[dl * 128 + lane * 2 + 0], bfpair_lo(v));
    atomicAdd(&acc[dl * 128 + lane * 2 + 1], bfpair_hi(v));
    if (lane == 0) atomicAdd(&dcnt[dl], 1);
  }
  __syncthreads();

  const int node = t >> 2;
  const int gq = (t & 3) * 32;
  const int n = n0 + node;
  if (n < N) {
    const int d = dcnt[node];
    const float inv = 1.0f / (float)(d > 1 ? d : 1);
    #pragma unroll
    for (int j = 0; j < 32; j += 4) {
      uint2 sv = *reinterpret_cast<const uint2*>(hw2 + (size_t)n * 256 + 128 + gq + j);
      float4 bb = *reinterpret_cast<const float4*>(b2 + gq + j);
      float4 r;
      r.x = acc[node * 128 + gq + j + 0] * inv + bfpair_lo(sv.x) + bb.x;
      r.y = acc[node * 128 + gq + j + 1] * inv + bfpair_hi(sv.x) + bb.y;
      r.z = acc[node * 128 + gq + j + 2] * inv + bfpair_lo(sv.y) + bb.z;
      r.w = acc[node * 128 + gq + j + 3] * inv + bfpair_hi(sv.y) + bb.w;
      *reinterpret_cast<float4*>(out + (size_t)n * 128 + gq + j) = r;
    }
  }
}

// --------------------------- FUSED double GEMM -----------------------------
__global__ __launch_bounds__(256) void gemm_fused_kernel(
    const __hip_bfloat16* __restrict__ A1,   // [M][256]
    const __hip_bfloat16* __restrict__ BT1,  // [256][256] = B1^T
    const __hip_bfloat16* __restrict__ BT2,  // [256][256] = B2^T
    const float* __restrict__ b1,            // [256]
    __hip_bfloat16* __restrict__ hw2,        // [M][256]
    int M) {
  __shared__ __hip_bfloat16 As[64 * 32];        // 4 KB
  __shared__ __hip_bfloat16 Bs[256 * 32];       // 16 KB
  __shared__ __hip_bfloat16 hLds[64 * 256];     // 32 KB, swizzled
  const int t = threadIdx.x;
  const int lane = t & 63;
  const int w = t >> 6;
  const int wc = w * 64;
  const int bm = blockIdx.x * 64;

  const int srow4 = lane >> 2;
  const int sbyte = (lane & 3) * 16;
  const int fr = lane & 15;
  const int fbyte = (lane >> 4) * 16;
  const int kslot = lane >> 4;

  f32x4 acc[4][4];
  #pragma unroll
  for (int i = 0; i < 4; ++i)
    #pragma unroll
    for (int j = 0; j < 4; ++j) acc[i][j] = (f32x4)(0.f);

  // phase 1: h = relu(A1 @ BT1^T + b1)
  for (int k0 = 0; k0 < 256; k0 += 32) {
    {
      int gr = bm + w * 16 + srow4;
      if (gr >= M) gr = M - 1;
      gload_lds16((const char*)A1 + (size_t)gr * 512 + k0 * 2 + sbyte,
                  (char*)As + w * 1024);
    }
    #pragma unroll
    for (int q = 0; q < 4; ++q) {
      const int c = w * 4 + q;
      const int row = c * 16 + srow4;
      gload_lds16((const char*)BT1 + (size_t)row * 512 + k0 * 2 + sbyte,
                  (char*)Bs + c * 1024);
    }
    __syncthreads();
    short8 af[4], bf[4];
    #pragma unroll
    for (int i = 0; i < 4; ++i) {
      af[i] = *reinterpret_cast<const short8*>((const char*)As + (fr + i * 16) * 64 + fbyte);
      bf[i] = *reinterpret_cast<const short8*>((const char*)Bs + (wc + fr + i * 16) * 64 + fbyte);
    }
    #pragma unroll
    for (int i = 0; i < 4; ++i)
      #pragma unroll
      for (int j = 0; j < 4; ++j)
        acc[i][j] = __builtin_amdgcn_mfma_f32_16x16x32_bf16(af[i], bf[j], acc[i][j], 0, 0, 0);
    __syncthreads();
  }

  // epilogue 1: bias + relu -> hLds (swizzled)
  {
    const int c0 = wc + fr;
    const int r0 = (lane >> 4) * 4;
    float bj[4];
    #pragma unroll
    for (int j = 0; j < 4; ++j) bj[j] = b1[c0 + j * 16];
    #pragma unroll
    for (int i = 0; i < 4; ++i) {
      #pragma unroll
      for (int j = 0; j < 4; ++j) {
        const int c = c0 + j * 16;
        #pragma unroll
        for (int q = 0; q < 4; ++q) {
          const int r = r0 + i * 16 + q;
          float v = fmaxf(acc[i][j][q] + bj[j], 0.f);
          const int byte = r * 512 + (((c >> 3) ^ (r & 7)) << 4) + ((c & 7) << 1);
          *reinterpret_cast<__hip_bfloat16*>((char*)hLds + byte) = __float2bfloat16(v);
        }
      }
    }
  }

  // phase 2: hw2 = h @ BT2^T
  #pragma unroll
  for (int i = 0; i < 4; ++i)
    #pragma unroll
    for (int j = 0; j < 4; ++j) acc[i][j] = (f32x4)(0.f);

  for (int k0 = 0; k0 < 256; k0 += 32) {
    #pragma unroll
    for (int q = 0; q < 4; ++q) {
      const int c = w * 4 + q;
      const int row = c * 16 + srow4;
      gload_lds16((const char*)BT2 + (size_t)row * 512 + k0 * 2 + sbyte,
                  (char*)Bs + c * 1024);
    }
    __syncthreads();
    short8 af[4], bf[4];
    const int ks = (k0 >> 3) + kslot;
    #pragma unroll
    for (int i = 0; i < 4; ++i) {
      const int ra = fr + i * 16;
      af[i] = *reinterpret_cast<const short8*>(
          (const char*)hLds + ra * 512 + ((ks ^ (ra & 7)) << 4));
      bf[i] = *reinterpret_cast<const short8*>((const char*)Bs + (wc + fr + i * 16) * 64 + fbyte);
    }
    #pragma unroll
    for (int i = 0; i < 4; ++i)
      #pragma unroll
      for (int j = 0; j < 4; ++j)
        acc[i][j] = __builtin_amdgcn_mfma_f32_16x16x32_bf16(af[i], bf[j], acc[i][j], 0, 0, 0);
    __syncthreads();
  }

  // epilogue 2
  {
    const int c0 = wc + fr;
    const int r0 = (lane >> 4) * 4;
    #pragma unroll
    for (int i = 0; i < 4; ++i) {
      #pragma unroll
      for (int q = 0; q < 4; ++q) {
        const int r = bm + r0 + i * 16 + q;
        if (r < M) {
          #pragma unroll
          for (int j = 0; j < 4; ++j)
            hw2[(size_t)r * 256 + c0 + j * 16] = __float2bfloat16(acc[i][j][q]);
        }
      }
    }
  }
}

// ------------------------------ launcher -----------------------------------

extern "C" void kernel_launch(void* const* d_in, const int* in_sizes, int n_in,
                              void* d_out, int out_size, void* d_ws, size_t ws_size,
                              hipStream_t stream) {
  const float* x    = (const float*)d_in[0];
  const int*   edge = (const int*)d_in[1];
  const float* W1_l = (const float*)d_in[2];
  const float* b1   = (const float*)d_in[3];
  const float* W1_r = (const float*)d_in[4];
  const float* W2_l = (const float*)d_in[5];
  const float* b2   = (const float*)d_in[6];
  const float* W2_r = (const float*)d_in[7];
  float* out = (float*)d_out;

  const int N = in_sizes[0] / 128;  // 50000 (packing assumes N <= 65536)
  const int E = in_sizes[1] / 2;
  const int* srcv = edge;
  const int* dstv = edge + E;
  const int NB = (N + (1 << BSHIFT) - 1) >> BSHIFT;  // 782 (<= 1024)

  char* ws = (char*)d_ws;
  size_t off = 0;
  auto alloc = [&](size_t bytes) -> void* {
    void* p = ws + off;
    off += align_up(bytes, 256);
    return p;
  };
  int* brow      = (int*)alloc((size_t)(NB + 1) * 4);
  int* btot      = (int*)alloc(1024 * 4);
  int* blockhist = (int*)alloc((size_t)PB * 1024 * 4);
  unsigned* stage = (unsigned*)alloc((size_t)E * 4);
  __hip_bfloat16* BT1 = (__hip_bfloat16*)alloc(256 * 256 * 2);
  __hip_bfloat16* BT2 = (__hip_bfloat16*)alloc(256 * 256 * 2);
  __hip_bfloat16* A1  = (__hip_bfloat16*)alloc((size_t)N * 256 * 2);
  __hip_bfloat16* hw2 = (__hip_bfloat16*)alloc((size_t)N * 256 * 2);

  const int chunk = (E + PB - 1) / PB;
  const int conv_blocks = (N * 32 + 255) / 256;
  setup_kernel<<<PB + 512 + conv_blocks, 256, 0, stream>>>(
      dstv, blockhist, E, chunk, x, W1_l, W1_r, W2_l, W2_r, BT1, BT2, A1, N * 32);

  colscan_kernel<<<256, 256, 0, stream>>>(blockhist, btot);
  bin2_kernel<<<PB, 256, 0, stream>>>(srcv, dstv, blockhist, btot, stage, brow, E, NB, chunk);

  agg1s_kernel<<<NB, 256, 0, stream>>>(stage, brow, A1, N);

  gemm_fused_kernel<<<(N + 63) / 64, 256, 0, stream>>>(A1, BT1, BT2, b1, hw2, N);

  agg2s_kernel<<<NB, 256, 0, stream>>>(stage, brow, hw2, b2, out, N);
}

// Round 13
// 133.640 us; speedup vs baseline: 10.7969x; 10.7969x over previous
//
#include <hip/hip_runtime.h>
#include <hip/hip_bf16.h>
#include <cstdint>

// ---------------------------------------------------------------------------
// SAGE GNN, 2 layers, N=50000, E=800000, D: 128 -> 256 -> 128.
// 7 kernels (round-11 structure — best measured: 133.7 us):
//   setup:    bhist rows (blocks 0..PB-1) + bf16^T weights + A1[:,128:256]
//   colscan:  one wave per bucket: shfl-scan PB per-block counts -> prefixes+btot
//   bin2:     btot scan + own-prefix row -> cursors; bin edges -> stage; brow
//   scatter2b: block/bucket, per-node deg+scan in LDS -> rowptr, col(u16)
//   agg1/agg2: wave/node gathers, REGISTER accumulation (2 edges/wave,
//             16 rows in flight)  [LDS-atomic variant measured 10x worse]
//   gemm_fused: h = relu(A1@W1+b1) -> LDS (swizzled); hw2 = h@[W2l|W2r]
// ---------------------------------------------------------------------------

static inline size_t align_up(size_t x, size_t a) { return (x + a - 1) & ~(a - 1); }

using short8 = __attribute__((ext_vector_type(8))) short;
using f32x4  = __attribute__((ext_vector_type(4))) float;

#define BSHIFT 6   // 64 nodes per bucket; NB = ceil(N/64) = 782 (<= 1024)
#define PB 128     // partition blocks for hist/bin (<= 128 for colscan)

__device__ __forceinline__ float bfpair_lo(unsigned int v) {
  union { unsigned int i; float f; } u; u.i = v << 16; return u.f;
}
__device__ __forceinline__ float bfpair_hi(unsigned int v) {
  union { unsigned int i; float f; } u; u.i = v & 0xffff0000u; return u.f;
}
__device__ __forceinline__ unsigned short f2bf(float f) {
  union { float f; unsigned int i; } u; u.f = f;
  unsigned int r = u.i + 0x7fffu + ((u.i >> 16) & 1u);
  return (unsigned short)(r >> 16);
}

__device__ __forceinline__ void gload_lds16(const void* g, void* l) {
  __builtin_amdgcn_global_load_lds(
      (const __attribute__((address_space(1))) void*)g,
      (__attribute__((address_space(3))) void*)l, 16, 0, 0);
}

// ------------------- setup: bhist + weights + x convert --------------------
__global__ __launch_bounds__(256) void setup_kernel(
    const int* __restrict__ dst, int* __restrict__ blockhist, int E, int chunk,
    const float* __restrict__ x,
    const float* __restrict__ W1l, const float* __restrict__ W1r,
    const float* __restrict__ W2l, const float* __restrict__ W2r,
    __hip_bfloat16* __restrict__ BT1, __hip_bfloat16* __restrict__ BT2,
    __hip_bfloat16* __restrict__ A1, int total4) {
  __shared__ int h[1024];
  const int bb = blockIdx.x;
  const int t = threadIdx.x;
  if (bb < PB) {  // per-block bucket histogram, plain coalesced row stores
    #pragma unroll
    for (int i = t; i < 1024; i += 256) h[i] = 0;
    __syncthreads();
    const int e0 = bb * chunk;
    int e1 = e0 + chunk; if (e1 > E) e1 = E;
    for (int e = e0 + t; e < e1; e += 256) atomicAdd(&h[dst[e] >> BSHIFT], 1);
    __syncthreads();
    #pragma unroll
    for (int i = t; i < 1024; i += 256) blockhist[bb * 1024 + i] = h[i];
    return;
  }
  const int wb = bb - PB;
  if (wb < 512) {  // weights: BT1[n][k], BT2[n][k]
    int idx = (wb & 255) * 256 + t;
    int n = idx >> 8, k = idx & 255;
    if (wb < 256) {
      float v = (k < 128) ? W1l[k * 256 + n] : W1r[(k - 128) * 256 + n];
      BT1[idx] = __float2bfloat16(v);
    } else {
      float v = (n < 128) ? W2l[k * 128 + n] : W2r[k * 128 + (n - 128)];
      BT2[idx] = __float2bfloat16(v);
    }
    return;
  }
  int idx = (wb - 512) * 256 + t;
  if (idx >= total4) return;
  int i = idx >> 5, j4 = (idx & 31) << 2;
  float4 v = *reinterpret_cast<const float4*>(x + (size_t)i * 128 + j4);
  unsigned p0 = ((unsigned)f2bf(v.y) << 16) | f2bf(v.x);
  unsigned p1 = ((unsigned)f2bf(v.w) << 16) | f2bf(v.z);
  *reinterpret_cast<uint2*>(A1 + (size_t)i * 256 + 128 + j4) = make_uint2(p0, p1);
}

// ---------- colscan: one wave per bucket, shfl-scan over PB blocks ---------
__global__ __launch_bounds__(256) void colscan_kernel(int* __restrict__ blockhist,
                                                      int* __restrict__ btot) {
  const int t = threadIdx.x;
  const int lane = t & 63;
  const int i = blockIdx.x * 4 + (t >> 6);  // bucket id, grid = 256 blocks
  int v0 = blockhist[lane * 1024 + i];
  int v1 = (64 + lane < PB) ? blockhist[(64 + lane) * 1024 + i] : 0;
  int s0 = v0, s1 = v1;
  #pragma unroll
  for (int off = 1; off < 64; off <<= 1) {
    int u0 = __shfl_up(s0, off, 64);
    int u1 = __shfl_up(s1, off, 64);
    if (lane >= off) { s0 += u0; s1 += u1; }
  }
  const int total0 = __shfl(s0, 63, 64);
  const int total1 = __shfl(s1, 63, 64);
  blockhist[lane * 1024 + i] = s0 - v0;
  if (64 + lane < PB) blockhist[(64 + lane) * 1024 + i] = total0 + s1 - v1;
  if (lane == 0) btot[i] = total0 + total1;
}

// --------------- bin2: bucket-base scan + bin (all coalesced) --------------
__global__ __launch_bounds__(256) void bin2_kernel(const int* __restrict__ src,
                                                   const int* __restrict__ dst,
                                                   const int* __restrict__ blockhist,
                                                   const int* __restrict__ btot,
                                                   unsigned* __restrict__ stage,
                                                   int* __restrict__ brow,
                                                   int E, int NB, int chunk) {
  __shared__ int cur_lds[1024];
  __shared__ int wsum[4];
  const int t = threadIdx.x;
  const int pb = blockIdx.x;

  // block-wide exclusive scan of the 1024 bucket totals
  int4 v = *reinterpret_cast<const int4*>(btot + t * 4);
  int tsum = v.x + v.y + v.z + v.w;
  const int lane = t & 63, w = t >> 6;
  int inc = tsum;
  #pragma unroll
  for (int off = 1; off < 64; off <<= 1) {
    int u = __shfl_up(inc, off, 64);
    if (lane >= off) inc += u;
  }
  if (lane == 63) wsum[w] = inc;
  __syncthreads();
  int woff = 0;
  for (int k = 0; k < w; ++k) woff += wsum[k];
  int e0x = woff + inc - tsum;
  int p0 = e0x, p1 = p0 + v.x, p2 = p1 + v.y, p3 = p2 + v.z;

  // cursors = bucket base + this block's own prefix (coalesced int4 row read)
  int4 o = *reinterpret_cast<const int4*>(blockhist + pb * 1024 + t * 4);
  cur_lds[t * 4 + 0] = p0 + o.x;
  cur_lds[t * 4 + 1] = p1 + o.y;
  cur_lds[t * 4 + 2] = p2 + o.z;
  cur_lds[t * 4 + 3] = p3 + o.w;
  if (pb == 0) {  // publish brow for scatter2b
    if (t * 4 + 0 < NB) brow[t * 4 + 0] = p0;
    if (t * 4 + 1 < NB) brow[t * 4 + 1] = p1;
    if (t * 4 + 2 < NB) brow[t * 4 + 2] = p2;
    if (t * 4 + 3 < NB) brow[t * 4 + 3] = p3;
    if (t == 255) brow[NB] = p3 + v.w;
  }
  __syncthreads();

  // bin this block's edge chunk via LDS cursors
  const int e0 = pb * chunk;
  const int e1 = min(e0 + chunk, E);
  for (int e = e0 + t; e < e1; e += 256) {
    int d = dst[e];
    int p = atomicAdd(&cur_lds[d >> BSHIFT], 1);
    stage[p] = (unsigned)src[e] | ((unsigned)(d & 63) << 16);
  }
}

// one block per bucket: node-local deg count + scan in LDS -> rowptr, col(u16)
__global__ __launch_bounds__(256) void scatter2b_kernel(const unsigned* __restrict__ stage,
                                                        const int* __restrict__ brow,
                                                        int* __restrict__ rowptr,
                                                        unsigned short* __restrict__ col,
                                                        int N, int E) {
  __shared__ int dcnt[64];
  __shared__ int dbase[64];
  const int b = blockIdx.x;
  const int t = threadIdx.x;
  const int n0 = b << BSHIFT;
  const int lo = brow[b], hi = brow[b + 1];
  if (t < 64) dcnt[t] = 0;
  __syncthreads();
  for (int e = lo + t; e < hi; e += 256) atomicAdd(&dcnt[stage[e] >> 16], 1);
  __syncthreads();
  if (t < 64) {
    int v = dcnt[t];
    int inc = v;
    #pragma unroll
    for (int off = 1; off < 64; off <<= 1) {
      int u = __shfl_up(inc, off, 64);
      if (t >= off) inc += u;
    }
    int excl = lo + inc - v;
    dbase[t] = excl;
    dcnt[t] = 0;  // reuse as cursor
    if (n0 + t < N) rowptr[n0 + t] = excl;
  }
  if (b == 0 && t == 0) rowptr[N] = E;
  __syncthreads();
  for (int e = lo + t; e < hi; e += 256) {
    unsigned pr = stage[e];
    int d = pr >> 16;
    int p = atomicAdd(&dcnt[d], 1);
    col[dbase[d] + p] = (unsigned short)(pr & 0xffffu);
  }
}

// ------------------------------ aggregations -------------------------------
// one wave per node, 2 edges/wave: lanes 0-31 = edge e, lanes 32-63 = e+1;
// each lane loads uint2 (4 bf16 cols). Main loop: 16 edges = 16 rows in
// flight. Tiered 8/4/2/1 tails keep MLP for low-degree nodes.

#define AGG_LOAD(TBL, OFFS)                                                    \
  {                                                                            \
    int s = col[eidx];                                                         \
    uint2 vv = *reinterpret_cast<const uint2*>(TBL + (size_t)s * 256 + OFFS + q * 4); \
    a0 += bfpair_lo(vv.x); a1 += bfpair_hi(vv.x);                              \
    a2 += bfpair_lo(vv.y); a3 += bfpair_hi(vv.y);                              \
  }

__global__ __launch_bounds__(64) void agg1_kernel(const int* __restrict__ rowptr,
                                                  const unsigned short* __restrict__ col,
                                                  __hip_bfloat16* __restrict__ A1) {
  const int i = blockIdx.x;
  const int t = threadIdx.x;
  const int half = t >> 5;
  const int q = t & 31;
  const int beg = rowptr[i], end = rowptr[i + 1];
  float a0 = 0.f, a1 = 0.f, a2 = 0.f, a3 = 0.f;
  int e = beg;
  for (; e + 15 < end; e += 16) {
    #pragma unroll
    for (int u = 0; u < 8; ++u) {
      int eidx = e + 2 * u + half;
      AGG_LOAD(A1, 128)
    }
  }
  if (e + 7 < end) {
    #pragma unroll
    for (int u = 0; u < 4; ++u) {
      int eidx = e + 2 * u + half;
      AGG_LOAD(A1, 128)
    }
    e += 8;
  }
  if (e + 3 < end) {
    #pragma unroll
    for (int u = 0; u < 2; ++u) {
      int eidx = e + 2 * u + half;
      AGG_LOAD(A1, 128)
    }
    e += 4;
  }
  if (e + 1 < end) {
    int eidx = e + half;
    AGG_LOAD(A1, 128)
    e += 2;
  }
  if (e < end && half == 0) {
    int eidx = e;
    AGG_LOAD(A1, 128)
  }
  a0 += __shfl_xor(a0, 32, 64);
  a1 += __shfl_xor(a1, 32, 64);
  a2 += __shfl_xor(a2, 32, 64);
  a3 += __shfl_xor(a3, 32, 64);
  const int d = end - beg;
  const float inv = 1.0f / (float)(d > 1 ? d : 1);
  if (half == 0) {
    unsigned p0 = ((unsigned)f2bf(a1 * inv) << 16) | f2bf(a0 * inv);
    unsigned p1 = ((unsigned)f2bf(a3 * inv) << 16) | f2bf(a2 * inv);
    *reinterpret_cast<uint2*>(A1 + (size_t)i * 256 + q * 4) = make_uint2(p0, p1);
  }
}

__global__ __launch_bounds__(64) void agg2_kernel(const __hip_bfloat16* __restrict__ hw2,
                                                  const int* __restrict__ rowptr,
                                                  const unsigned short* __restrict__ col,
                                                  const float* __restrict__ b2,
                                                  float* __restrict__ out) {
  const int i = blockIdx.x;
  const int t = threadIdx.x;
  const int half = t >> 5;
  const int q = t & 31;
  const int beg = rowptr[i], end = rowptr[i + 1];
  float a0 = 0.f, a1 = 0.f, a2 = 0.f, a3 = 0.f;
  int e = beg;
  for (; e + 15 < end; e += 16) {
    #pragma unroll
    for (int u = 0; u < 8; ++u) {
      int eidx = e + 2 * u + half;
      AGG_LOAD(hw2, 0)
    }
  }
  if (e + 7 < end) {
    #pragma unroll
    for (int u = 0; u < 4; ++u) {
      int eidx = e + 2 * u + half;
      AGG_LOAD(hw2, 0)
    }
    e += 8;
  }
  if (e + 3 < end) {
    #pragma unroll
    for (int u = 0; u < 2; ++u) {
      int eidx = e + 2 * u + half;
      AGG_LOAD(hw2, 0)
    }
    e += 4;
  }
  if (e + 1 < end) {
    int eidx = e + half;
    AGG_LOAD(hw2, 0)
    e += 2;
  }
  if (e < end && half == 0) {
    int eidx = e;
    AGG_LOAD(hw2, 0)
  }
  a0 += __shfl_xor(a0, 32, 64);
  a1 += __shfl_xor(a1, 32, 64);
  a2 += __shfl_xor(a2, 32, 64);
  a3 += __shfl_xor(a3, 32, 64);
  const int d = end - beg;
  const float inv = 1.0f / (float)(d > 1 ? d : 1);
  if (half == 0) {
    uint2 sv = *reinterpret_cast<const uint2*>(hw2 + (size_t)i * 256 + 128 + q * 4);
    float4 bb = *reinterpret_cast<const float4*>(b2 + q * 4);
    float4 r;
    r.x = a0 * inv + bfpair_lo(sv.x) + bb.x;
    r.y = a1 * inv + bfpair_hi(sv.x) + bb.y;
    r.z = a2 * inv + bfpair_lo(sv.y) + bb.z;
    r.w = a3 * inv + bfpair_hi(sv.y) + bb.w;
    *reinterpret_cast<float4*>(out + (size_t)i * 128 + q * 4) = r;
  }
}

// --------------------------- FUSED double GEMM -----------------------------
__global__ __launch_bounds__(256) void gemm_fused_kernel(
    const __hip_bfloat16* __restrict__ A1,   // [M][256]
    const __hip_bfloat16* __restrict__ BT1,  // [256][256] = B1^T
    const __hip_bfloat16* __restrict__ BT2,  // [256][256] = B2^T
    const float* __restrict__ b1,            // [256]
    __hip_bfloat16* __restrict__ hw2,        // [M][256]
    int M) {
  __shared__ __hip_bfloat16 As[64 * 32];        // 4 KB
  __shared__ __hip_bfloat16 Bs[256 * 32];       // 16 KB
  __shared__ __hip_bfloat16 hLds[64 * 256];     // 32 KB, swizzled
  const int t = threadIdx.x;
  const int lane = t & 63;
  const int w = t >> 6;
  const int wc = w * 64;
  const int bm = blockIdx.x * 64;

  const int srow4 = lane >> 2;
  const int sbyte = (lane & 3) * 16;
  const int fr = lane & 15;
  const int fbyte = (lane >> 4) * 16;
  const int kslot = lane >> 4;

  f32x4 acc[4][4];
  #pragma unroll
  for (int i = 0; i < 4; ++i)
    #pragma unroll
    for (int j = 0; j < 4; ++j) acc[i][j] = (f32x4)(0.f);

  // phase 1: h = relu(A1 @ BT1^T + b1)
  for (int k0 = 0; k0 < 256; k0 += 32) {
    {
      int gr = bm + w * 16 + srow4;
      if (gr >= M) gr = M - 1;
      gload_lds16((const char*)A1 + (size_t)gr * 512 + k0 * 2 + sbyte,
                  (char*)As + w * 1024);
    }
    #pragma unroll
    for (int q = 0; q < 4; ++q) {
      const int c = w * 4 + q;
      const int row = c * 16 + srow4;
      gload_lds16((const char*)BT1 + (size_t)row * 512 + k0 * 2 + sbyte,
                  (char*)Bs + c * 1024);
    }
    __syncthreads();
    short8 af[4], bf[4];
    #pragma unroll
    for (int i = 0; i < 4; ++i) {
      af[i] = *reinterpret_cast<const short8*>((const char*)As + (fr + i * 16) * 64 + fbyte);
      bf[i] = *reinterpret_cast<const short8*>((const char*)Bs + (wc + fr + i * 16) * 64 + fbyte);
    }
    #pragma unroll
    for (int i = 0; i < 4; ++i)
      #pragma unroll
      for (int j = 0; j < 4; ++j)
        acc[i][j] = __builtin_amdgcn_mfma_f32_16x16x32_bf16(af[i], bf[j], acc[i][j], 0, 0, 0);
    __syncthreads();
  }

  // epilogue 1: bias + relu -> hLds (swizzled)
  {
    const int c0 = wc + fr;
    const int r0 = (lane >> 4) * 4;
    float bj[4];
    #pragma unroll
    for (int j = 0; j < 4; ++j) bj[j] = b1[c0 + j * 16];
    #pragma unroll
    for (int i = 0; i < 4; ++i) {
      #pragma unroll
      for (int j = 0; j < 4; ++j) {
        const int c = c0 + j * 16;
        #pragma unroll
        for (int q = 0; q < 4; ++q) {
          const int r = r0 + i * 16 + q;
          float v = fmaxf(acc[i][j][q] + bj[j], 0.f);
          const int byte = r * 512 + (((c >> 3) ^ (r & 7)) << 4) + ((c & 7) << 1);
          *reinterpret_cast<__hip_bfloat16*>((char*)hLds + byte) = __float2bfloat16(v);
        }
      }
    }
  }

  // phase 2: hw2 = h @ BT2^T
  #pragma unroll
  for (int i = 0; i < 4; ++i)
    #pragma unroll
    for (int j = 0; j < 4; ++j) acc[i][j] = (f32x4)(0.f);

  for (int k0 = 0; k0 < 256; k0 += 32) {
    #pragma unroll
    for (int q = 0; q < 4; ++q) {
      const int c = w * 4 + q;
      const int row = c * 16 + srow4;
      gload_lds16((const char*)BT2 + (size_t)row * 512 + k0 * 2 + sbyte,
                  (char*)Bs + c * 1024);
    }
    __syncthreads();
    short8 af[4], bf[4];
    const int ks = (k0 >> 3) + kslot;
    #pragma unroll
    for (int i = 0; i < 4; ++i) {
      const int ra = fr + i * 16;
      af[i] = *reinterpret_cast<const short8*>(
          (const char*)hLds + ra * 512 + ((ks ^ (ra & 7)) << 4));
      bf[i] = *reinterpret_cast<const short8*>((const char*)Bs + (wc + fr + i * 16) * 64 + fbyte);
    }
    #pragma unroll
    for (int i = 0; i < 4; ++i)
      #pragma unroll
      for (int j = 0; j < 4; ++j)
        acc[i][j] = __builtin_amdgcn_mfma_f32_16x16x32_bf16(af[i], bf[j], acc[i][j], 0, 0, 0);
    __syncthreads();
  }

  // epilogue 2
  {
    const int c0 = wc + fr;
    const int r0 = (lane >> 4) * 4;
    #pragma unroll
    for (int i = 0; i < 4; ++i) {
      #pragma unroll
      for (int q = 0; q < 4; ++q) {
        const int r = bm + r0 + i * 16 + q;
        if (r < M) {
          #pragma unroll
          for (int j = 0; j < 4; ++j)
            hw2[(size_t)r * 256 + c0 + j * 16] = __float2bfloat16(acc[i][j][q]);
        }
      }
    }
  }
}

// ------------------------------ launcher -----------------------------------

extern "C" void kernel_launch(void* const* d_in, const int* in_sizes, int n_in,
                              void* d_out, int out_size, void* d_ws, size_t ws_size,
                              hipStream_t stream) {
  const float* x    = (const float*)d_in[0];
  const int*   edge = (const int*)d_in[1];
  const float* W1_l = (const float*)d_in[2];
  const float* b1   = (const float*)d_in[3];
  const float* W1_r = (const float*)d_in[4];
  const float* W2_l = (const float*)d_in[5];
  const float* b2   = (const float*)d_in[6];
  const float* W2_r = (const float*)d_in[7];
  float* out = (float*)d_out;

  const int N = in_sizes[0] / 128;  // 50000 (packing assumes N <= 65536)
  const int E = in_sizes[1] / 2;
  const int* srcv = edge;
  const int* dstv = edge + E;
  const int NB = (N + (1 << BSHIFT) - 1) >> BSHIFT;  // 782 (<= 1024)

  char* ws = (char*)d_ws;
  size_t off = 0;
  auto alloc = [&](size_t bytes) -> void* {
    void* p = ws + off;
    off += align_up(bytes, 256);
    return p;
  };
  int* rowptr    = (int*)alloc((size_t)(N + 1) * 4);
  int* brow      = (int*)alloc((size_t)(NB + 1) * 4);
  int* btot      = (int*)alloc(1024 * 4);
  int* blockhist = (int*)alloc((size_t)PB * 1024 * 4);
  unsigned short* col = (unsigned short*)alloc((size_t)E * 2);
  unsigned* stage = (unsigned*)alloc((size_t)E * 4);
  __hip_bfloat16* BT1 = (__hip_bfloat16*)alloc(256 * 256 * 2);
  __hip_bfloat16* BT2 = (__hip_bfloat16*)alloc(256 * 256 * 2);
  __hip_bfloat16* A1  = (__hip_bfloat16*)alloc((size_t)N * 256 * 2);
  __hip_bfloat16* hw2 = (__hip_bfloat16*)alloc((size_t)N * 256 * 2);

  const int chunk = (E + PB - 1) / PB;
  const int conv_blocks = (N * 32 + 255) / 256;
  setup_kernel<<<PB + 512 + conv_blocks, 256, 0, stream>>>(
      dstv, blockhist, E, chunk, x, W1_l, W1_r, W2_l, W2_r, BT1, BT2, A1, N * 32);

  colscan_kernel<<<256, 256, 0, stream>>>(blockhist, btot);
  bin2_kernel<<<PB, 256, 0, stream>>>(srcv, dstv, blockhist, btot, stage, brow, E, NB, chunk);
  scatter2b_kernel<<<NB, 256, 0, stream>>>(stage, brow, rowptr, col, N, E);

  agg1_kernel<<<N, 64, 0, stream>>>(rowptr, col, A1);

  gemm_fused_kernel<<<(N + 63) / 64, 256, 0, stream>>>(A1, BT1, BT2, b1, hw2, N);

  agg2_kernel<<<N, 64, 0, stream>>>(hw2, rowptr, col, b2, out);
}